// Round 4
// baseline (159.638 us; speedup 1.0000x reference)
//
#include <hip/hip_runtime.h>
#include <hip/hip_bf16.h>
#include <hip/hip_cooperative_groups.h>

namespace cg = cooperative_groups;

// Problem constants (fixed by reference)
#define NPTS  8192
#define GXD   334
#define GYD   334
#define GZD   2
#define HSIZE 16384
#define HMASK 16383
#define KADJ  50
#define TROUNDS 24

#define NBLK  64
#define NTHR  1024    // 64 x 1024 = 65536 threads, 1024 waves

__device__ __forceinline__ unsigned hashv(unsigned v) {
    unsigned h = v * 2654435761u;
    h ^= h >> 15;
    return h & HMASK;
}

__device__ __forceinline__ void voxel_coords(float x, float y, float z,
                                             int& cx, int& cy, int& cz) {
    // Mirror ref exactly: floor((p - PC_MIN) / VOXEL), clip after cast.
    cx = (int)floorf((x - (-50.0f)) / 0.3f);
    cy = (int)floorf((y - (-50.0f)) / 0.3f);
    cz = (int)floorf((z - (-5.0f))  / 6.0f);
    cx = min(max(cx, 0), GXD - 1);
    cy = min(max(cy, 0), GYD - 1);
    cz = min(max(cz, 0), GZD - 1);
}

__device__ __forceinline__ int hlookup(const int* __restrict__ hkey, int vid) {
    unsigned h = hashv((unsigned)vid);
    for (;;) {
        int k = hkey[h];
        if (k == vid) return (int)h;
        if (k == -1)  return -1;
        h = (h + 1) & HMASK;
    }
}

__global__ void __launch_bounds__(NTHR) k_fused(const float* __restrict__ pts,
                                                const int* __restrict__ bidx,
                                                int* hkey, float* hcnt,
                                                float* hsx, float* hsy, float* hsz,
                                                int* hrep, int* pslot,
                                                int* deg, int* adj,
                                                float* __restrict__ out) {
    cg::grid_group grid = cg::this_grid();
    int tid = blockIdx.x * NTHR + threadIdx.x;     // 0..65535

    // ---------------- Phase 0: hash-table init (replaces 3 memset dispatches)
    if (tid < HSIZE) {
        hkey[tid] = -1;
        hrep[tid] = 0x7FFFFFFF;
        hcnt[tid] = 0.0f;
        hsx[tid]  = 0.0f;
        hsy[tid]  = 0.0f;
        hsz[tid]  = 0.0f;
    }
    grid.sync();

    // ---------------- Phase 1: voxel accumulate (CAS insert + atomics)
    if (tid < NPTS) {
        int i = tid;
        float x = pts[3 * i + 0], y = pts[3 * i + 1], z = pts[3 * i + 2];
        int cx, cy, cz;
        voxel_coords(x, y, z, cx, cy, cz);
        int b = bidx[i];
        int vid = ((b * GZD + cz) * GYD + cy) * GXD + cx;
        unsigned h = hashv((unsigned)vid);
        int slot;
        for (;;) {
            int prev = atomicCAS(&hkey[h], -1, vid);
            if (prev == -1 || prev == vid) { slot = (int)h; break; }
            h = (h + 1) & HMASK;
        }
        atomicAdd(&hcnt[slot], 1.0f);
        atomicAdd(&hsx[slot], x);
        atomicAdd(&hsy[slot], y);
        atomicAdd(&hsz[slot], z);
        atomicMin(&hrep[slot], i);
        pslot[i] = slot;            // plain store -> fence before sync
    }
    __threadfence();
    grid.sync();

    // ---------------- Phase 2: adjacency gather, one wave per point (8 pts/wave)
    {
        int w    = tid >> 6;        // 0..1023
        int lane = tid & 63;
        for (int k = 0; k < 8; k++) {
            int i = w * 8 + k;      // < NPTS always

            // wave-uniform loads
            float x = pts[3 * i + 0], y = pts[3 * i + 1], z = pts[3 * i + 2];
            int cx, cy, cz;
            voxel_coords(x, y, z, cx, cy, cz);
            int b    = bidx[i];
            int slot = pslot[i];

            // own center == ref: sums / max(cnt,1), same f32 division
            float cn  = fmaxf(hcnt[slot], 1.0f);
            float cxf = hsx[slot] / cn;
            float cyf = hsy[slot] / cn;
            float czf = hsz[slot] / cn;

            bool pred = false;
            int  rep  = 0;
            if (lane < KADJ) {
                int zz  = lane / 25;
                int rem = lane % 25;
                int dy  = rem / 5 - 2;
                int dx  = rem % 5 - 2;
                int ny = cy + dy, nx = cx + dx;
                if (ny >= 0 && ny < GYD && nx >= 0 && nx < GXD) {
                    int nvid = ((b * GZD + zz) * GYD + ny) * GXD + nx;
                    int s = hlookup(hkey, nvid);
                    if (s >= 0) {
                        float ncn = fmaxf(hcnt[s], 1.0f);
                        float nxc = hsx[s] / ncn;
                        float nyc = hsy[s] / ncn;
                        float ddx = cxf - nxc;
                        float ddy = cyf - nyc;
                        // separate roundings like ref (no FMA contraction)
                        float sq = __fadd_rn(__fmul_rn(ddx, ddx), __fmul_rn(ddy, ddy));
                        if (sqrtf(sq) < 0.6f) {
                            pred = true;
                            rep  = hrep[s];  // representative = min point idx in voxel
                        }
                    }
                }
            }
            unsigned long long mask = __ballot(pred);
            if (pred) {
                int rank = __popcll(mask & ((1ull << lane) - 1ull));
                adj[i * KADJ + rank] = rep;
            }
            if (lane == 0) {
                deg[i] = __popcll(mask);
                // float32 outputs: cluster_inds interleaved [b,c], valid, cpp
                out[2 * i]                = (float)b;
                out[2 * NPTS + i]         = 1.0f;   // cnt >= MIN_POINTS=1 always
                out[3 * NPTS + 3 * i + 0] = cxf;
                out[3 * NPTS + 3 * i + 1] = cyf;
                out[3 * NPTS + 3 * i + 2] = czf;
            }
        }
    }
    __threadfence();
    grid.sync();

    // ---------------- Phase 3: CC on block 0 only (labels in LDS, early exit).
    // Labels monotone-decreasing, always an index of a same-component vertex; a
    // no-change round implies per-component-constant labels == component min,
    // exactly the reference fixed point.
    if (blockIdx.x == 0) {
        __shared__ int l[NPTS];
        __shared__ int changed;
        int t = threadIdx.x;
        for (int i = t; i < NPTS; i += NTHR) l[i] = i;
        __syncthreads();
        for (int r = 0; r < TROUNDS; r++) {
            __syncthreads();
            if (t == 0) changed = 0;
            __syncthreads();
            for (int i = t; i < NPTS; i += NTHR) {
                int old = l[i];
                int m = old;
                int d = deg[i];
                const int* a = &adj[i * KADJ];
                for (int e = 0; e < d; e++) {
                    int lj = l[a[e]];
                    if (lj < m) m = lj;
                }
                if (m < old) {
                    atomicMin(&l[i], m);
                    atomicMin(&l[old], m);   // hook: merge at old root
                    changed = 1;
                }
            }
            __syncthreads();
            for (int jp = 0; jp < 2; jp++) {  // pointer jumping x2
                for (int i = t; i < NPTS; i += NTHR) {
                    int a2 = l[i];
                    int b2 = l[a2];
                    if (b2 < a2) { l[i] = b2; changed = 1; }
                }
                __syncthreads();
            }
            if (!changed) break;
        }
        for (int i = t; i < NPTS; i += NTHR)
            out[2 * i + 1] = (float)l[i];
    }
}

extern "C" void kernel_launch(void* const* d_in, const int* in_sizes, int n_in,
                              void* d_out, int out_size, void* d_ws, size_t ws_size,
                              hipStream_t stream) {
    const float* pts  = (const float*)d_in[0];
    const int*   bidx = (const int*)d_in[1];
    float* out = (float*)d_out;

    char* w = (char*)d_ws;
    int*   hkey  = (int*)  (w + 0);        // 16384 ints
    float* hcnt  = (float*)(w + 65536);
    float* hsx   = (float*)(w + 131072);
    float* hsy   = (float*)(w + 196608);
    float* hsz   = (float*)(w + 262144);
    int*   hrep  = (int*)  (w + 327680);
    int*   pslot = (int*)  (w + 589824);   // 8192 ints
    int*   deg   = (int*)  (w + 622592);   // 8192 ints
    int*   adj   = (int*)  (w + 655360);   // 8192*50 ints (~1.6 MB; total ws ~2.2 MB)

    void* args[] = {
        (void*)&pts, (void*)&bidx,
        (void*)&hkey, (void*)&hcnt, (void*)&hsx, (void*)&hsy, (void*)&hsz,
        (void*)&hrep, (void*)&pslot, (void*)&deg, (void*)&adj, (void*)&out
    };
    hipLaunchCooperativeKernel((const void*)k_fused, dim3(NBLK), dim3(NTHR),
                               args, 0, stream);
}